// Round 6
// baseline (380.689 us; speedup 1.0000x reference)
//
#include <hip/hip_runtime.h>
#include <hip/hip_bf16.h>

typedef __bf16 bf16x8 __attribute__((ext_vector_type(8)));
typedef float  f32x4  __attribute__((ext_vector_type(4)));

#define N_TOT   16384
#define K_TOT   16384
#define HALF_M  ((size_t)128 * 16384)
#define BN      128
#define BK      64
#define KSPLIT  4
#define KQ_LEN  (K_TOT / KSPLIT)      // 4096
#define NQSTEPS (KQ_LEN / BK)         // 64
#define KSTEPS_TOT (K_TOT / BK)       // 256 tile images in wsT
#define TILE_BYTES 32768              // 256 rows x 128 B
#define OUT_ELEMS ((size_t)256 * 16384)

__device__ __forceinline__ unsigned short f2bf(float f) {
    __hip_bfloat16 h = __float2bfloat16(f);
    return __builtin_bit_cast(unsigned short, h);
}

// Swizzled byte offset in a 128-B-row tile, 16-B granules, XOR row&7.
__device__ __forceinline__ int swz(int row, int g) {
    return row * 128 + (((g ^ (row & 7)) & 7) << 4);
}

__device__ __forceinline__ void load_lds16(const void* g, void* l) {
    __builtin_amdgcn_global_load_lds(
        (const __attribute__((address_space(1))) unsigned int*)g,
        (__attribute__((address_space(3))) unsigned int*)l, 16, 0, 0);
}

// T = concat(x0,x1) fp32 -> bf16, written as 256 pre-swizzled 32-KB tile
// images (one per 64-col k-step). Image byte b of tile ks lands at LDS byte b
// after a linear global_load_lds copy; the swizzle is baked into the SOURCE
// (rule #21: linear dest + inverse-swz source + swz on read).
__global__ void cvtT_kernel(const float* __restrict__ x0,
                            const float* __restrict__ x1,
                            unsigned short* __restrict__ wsT) {
    size_t i = (size_t)blockIdx.x * blockDim.x + threadIdx.x;  // 0..524287
    const int ks   = (int)(i >> 11);          // tile index 0..255
    const int rem  = (int)(i & 2047);
    const int r    = rem >> 3;                // row 0..255
    const int gimg = rem & 7;                 // granule slot in image
    const int g    = gimg ^ (r & 7);          // source granule (inverse swz)
    const float* src = (r < 128)
        ? (x0 + (size_t)r * K_TOT)
        : (x1 + (size_t)(r - 128) * K_TOT);
    src += ks * 64 + g * 8;
    float4 a = ((const float4*)src)[0];
    float4 b = ((const float4*)src)[1];
    union { unsigned short u[8]; uint4 v; } o;
    o.u[0] = f2bf(a.x); o.u[1] = f2bf(a.y); o.u[2] = f2bf(a.z); o.u[3] = f2bf(a.w);
    o.u[4] = f2bf(b.x); o.u[5] = f2bf(b.y); o.u[6] = f2bf(b.z); o.u[7] = f2bf(b.w);
    ((uint4*)wsT)[i] = o.v;                   // linear image write
}

// out += p0 + p1 + p2 (fixed order -> deterministic)
__global__ void combine_kernel(float* __restrict__ out,
                               const float* __restrict__ p0,
                               const float* __restrict__ p1,
                               const float* __restrict__ p2) {
    const size_t n4 = OUT_ELEMS / 4;
    size_t i = (size_t)blockIdx.x * blockDim.x + threadIdx.x;
    for (; i < n4; i += (size_t)gridDim.x * blockDim.x) {
        float4 o = ((const float4*)out)[i];
        float4 a = ((const float4*)p0)[i];
        float4 b = ((const float4*)p1)[i];
        float4 c = ((const float4*)p2)[i];
        o.x += a.x + b.x + c.x;  o.y += a.y + b.y + c.y;
        o.z += a.z + b.z + c.z;  o.w += a.w + b.w + c.w;
        ((float4*)out)[i] = o;
    }
}

// ---- W prefetch/stage (register path, depth-2 static sets) ----
#define ISSUEW(S, k0) do {                                                    \
    const float4* _q = (const float4*)(brow + (k0));                          \
    wb##S##_0 = _q[0]; wb##S##_1 = _q[1];                                     \
} while (0)

#define STAGEW(S, Bb) do {                                                    \
    union { unsigned short u[8]; uint4 v; } _tb;                              \
    _tb.u[0]=f2bf(wb##S##_0.x); _tb.u[1]=f2bf(wb##S##_0.y);                   \
    _tb.u[2]=f2bf(wb##S##_0.z); _tb.u[3]=f2bf(wb##S##_0.w);                   \
    _tb.u[4]=f2bf(wb##S##_1.x); _tb.u[5]=f2bf(wb##S##_1.y);                   \
    _tb.u[6]=f2bf(wb##S##_1.z); _tb.u[7]=f2bf(wb##S##_1.w);                   \
    *(uint4*)((Bb) + bw) = _tb.v;                                             \
} while (0)

// A-tile DMA: 2 x global_load_lds dwordx4 per wave (1 KB each), linear copy
// of the pre-swizzled tile image. Issued FIRST in each phase (vmcnt order!).
#define DMA_A(Ab, ks) do {                                                    \
    const char* _src = (const char*)wsT + (size_t)(ks) * TILE_BYTES + dma_go; \
    load_lds16(_src,        (Ab) + dma_lo);                                   \
    load_lds16(_src + 1024, (Ab) + dma_lo + 1024);                            \
} while (0)

// 16 waves as 4M x 4N over 256M x 128N: wave owns 64M x 32N.
#define COMPUTE(Ab, Bb) do {                                                  \
    bf16x8 _b00 = *(const bf16x8*)((Bb) + boff00);                            \
    bf16x8 _b01 = *(const bf16x8*)((Bb) + boff01);                            \
    bf16x8 _b10 = *(const bf16x8*)((Bb) + boff10);                            \
    bf16x8 _b11 = *(const bf16x8*)((Bb) + boff11);                            \
    bf16x8 _a;                                                                \
    _a = *(const bf16x8*)((Ab) + aoff00);                                     \
    acc00 = __builtin_amdgcn_mfma_f32_16x16x32_bf16(_a, _b00, acc00, 0, 0, 0);\
    acc01 = __builtin_amdgcn_mfma_f32_16x16x32_bf16(_a, _b10, acc01, 0, 0, 0);\
    _a = *(const bf16x8*)((Ab) + aoff01);                                     \
    acc00 = __builtin_amdgcn_mfma_f32_16x16x32_bf16(_a, _b01, acc00, 0, 0, 0);\
    acc01 = __builtin_amdgcn_mfma_f32_16x16x32_bf16(_a, _b11, acc01, 0, 0, 0);\
    _a = *(const bf16x8*)((Ab) + aoff10);                                     \
    acc10 = __builtin_amdgcn_mfma_f32_16x16x32_bf16(_a, _b00, acc10, 0, 0, 0);\
    acc11 = __builtin_amdgcn_mfma_f32_16x16x32_bf16(_a, _b10, acc11, 0, 0, 0);\
    _a = *(const bf16x8*)((Ab) + aoff11);                                     \
    acc10 = __builtin_amdgcn_mfma_f32_16x16x32_bf16(_a, _b01, acc10, 0, 0, 0);\
    acc11 = __builtin_amdgcn_mfma_f32_16x16x32_bf16(_a, _b11, acc11, 0, 0, 0);\
    _a = *(const bf16x8*)((Ab) + aoff20);                                     \
    acc20 = __builtin_amdgcn_mfma_f32_16x16x32_bf16(_a, _b00, acc20, 0, 0, 0);\
    acc21 = __builtin_amdgcn_mfma_f32_16x16x32_bf16(_a, _b10, acc21, 0, 0, 0);\
    _a = *(const bf16x8*)((Ab) + aoff21);                                     \
    acc20 = __builtin_amdgcn_mfma_f32_16x16x32_bf16(_a, _b01, acc20, 0, 0, 0);\
    acc21 = __builtin_amdgcn_mfma_f32_16x16x32_bf16(_a, _b11, acc21, 0, 0, 0);\
    _a = *(const bf16x8*)((Ab) + aoff30);                                     \
    acc30 = __builtin_amdgcn_mfma_f32_16x16x32_bf16(_a, _b00, acc30, 0, 0, 0);\
    acc31 = __builtin_amdgcn_mfma_f32_16x16x32_bf16(_a, _b10, acc31, 0, 0, 0);\
    _a = *(const bf16x8*)((Ab) + aoff31);                                     \
    acc30 = __builtin_amdgcn_mfma_f32_16x16x32_bf16(_a, _b01, acc30, 0, 0, 0);\
    acc31 = __builtin_amdgcn_mfma_f32_16x16x32_bf16(_a, _b11, acc31, 0, 0, 0);\
} while (0)

// Counted sync: vmcnt(2) completes this phase's A-DMA (issued first) while
// leaving the 2 newest W prefetch loads in flight across the barrier.
#define SYNCC do {                                                            \
    asm volatile("s_waitcnt vmcnt(2)" ::: "memory");                          \
    asm volatile("s_waitcnt lgkmcnt(0)" ::: "memory");                        \
    __builtin_amdgcn_s_barrier();                                             \
    __builtin_amdgcn_sched_barrier(0);                                        \
} while (0)

// GEMM: grid 512. XCD-aligned mapping: kq = (bid&7)>>1 so each XCD's L2
// holds exactly one 2.1 MB wsT slice; nstrip = (bid>>3)*2 + (bid&1).
__global__ __launch_bounds__(1024)
void gemm_ws(const float* __restrict__ W, const float* __restrict__ bias,
             const unsigned short* __restrict__ wsT,
             float* __restrict__ out, float* __restrict__ wsP)
{
    __shared__ uint4 smem_[(2 * TILE_BYTES + 2 * 16384) / 16];   // 96 KiB
    char* const sm = (char*)smem_;
    char* const A0 = sm;                       // A: 256 x 128 B (pre-swz image)
    char* const A1 = sm + TILE_BYTES;
    char* const B0 = sm + 2 * TILE_BYTES;      // B: 128 x 128 B
    char* const B1 = sm + 2 * TILE_BYTES + 16384;

    const int tid  = threadIdx.x;
    const int lane = tid & 63;
    const int wave = tid >> 6;
    const int wm = wave >> 2;                  // 0..3 (64 M rows)
    const int wn = wave & 3;                   // 0..3 (32 N cols)
    const int bid    = blockIdx.x;
    const int kq     = (bid & 7) >> 1;         // XCD pair -> k-quarter
    const int nstrip = ((bid >> 3) << 1) + (bid & 1);
    const int n0     = nstrip * BN;
    const int kbase  = kq * KQ_LEN;            // element offset
    const int ks0    = kq * NQSTEPS;           // tile-image offset

    // A-DMA geometry (per wave): 2 x 1 KB chunks
    const int dma_lo = wave * 2048;
    const int dma_go = wave * 2048 + lane * 16;

    // W staging geometry: 8 threads per row, 32 B (8 floats) each
    const int rbs = tid >> 3;                  // B row 0..127
    const float* brow = W + (size_t)(n0 + rbs) * K_TOT + kbase + (tid & 7) * 8;
    const int bw  = swz(rbs, tid & 7);

    // compute-side LDS read offsets
    const int aoff00 = swz(wm * 64 +  0 + (lane & 15), 0 + (lane >> 4));
    const int aoff01 = swz(wm * 64 +  0 + (lane & 15), 4 + (lane >> 4));
    const int aoff10 = swz(wm * 64 + 16 + (lane & 15), 0 + (lane >> 4));
    const int aoff11 = swz(wm * 64 + 16 + (lane & 15), 4 + (lane >> 4));
    const int aoff20 = swz(wm * 64 + 32 + (lane & 15), 0 + (lane >> 4));
    const int aoff21 = swz(wm * 64 + 32 + (lane & 15), 4 + (lane >> 4));
    const int aoff30 = swz(wm * 64 + 48 + (lane & 15), 0 + (lane >> 4));
    const int aoff31 = swz(wm * 64 + 48 + (lane & 15), 4 + (lane >> 4));
    const int boff00 = swz(wn * 32 +  0 + (lane & 15), 0 + (lane >> 4));
    const int boff01 = swz(wn * 32 +  0 + (lane & 15), 4 + (lane >> 4));
    const int boff10 = swz(wn * 32 + 16 + (lane & 15), 0 + (lane >> 4));
    const int boff11 = swz(wn * 32 + 16 + (lane & 15), 4 + (lane >> 4));

    f32x4 acc00 = {0.f,0.f,0.f,0.f}, acc01 = {0.f,0.f,0.f,0.f};
    f32x4 acc10 = {0.f,0.f,0.f,0.f}, acc11 = {0.f,0.f,0.f,0.f};
    f32x4 acc20 = {0.f,0.f,0.f,0.f}, acc21 = {0.f,0.f,0.f,0.f};
    f32x4 acc30 = {0.f,0.f,0.f,0.f}, acc31 = {0.f,0.f,0.f,0.f};

    float4 wb0_0, wb0_1, wb1_0, wb1_1;

    // prologue
    DMA_A(A0, ks0);
    __builtin_amdgcn_sched_barrier(0);
    ISSUEW(0, 0);
    ISSUEW(1, BK);
    STAGEW(0, B0);
    SYNCC;

    // uniform pipelined loop; indices clamped at the tail (reads stay
    // in-bounds inside this block's own slice; garbage stages land in
    // buffers that are never read again).
    for (int kt = 0; kt < NQSTEPS; kt += 2) {
        // phase even: compute tile kt (A0/B0); DMA A1(kt+1); issue W s0(kt+2)
        {
            const int kn = (kt + 1 < NQSTEPS) ? (kt + 1) : (NQSTEPS - 1);
            DMA_A(A1, ks0 + kn);
            __builtin_amdgcn_sched_barrier(0);
            const int kw = ((kt + 2 < NQSTEPS) ? (kt + 2) : (NQSTEPS - 1)) * BK;
            ISSUEW(0, kw);
            COMPUTE(A0, B0);
            STAGEW(1, B1);
            SYNCC;
        }
        // phase odd: compute tile kt+1 (A1/B1); DMA A0(kt+2); issue W s1(kt+3)
        {
            const int kn = (kt + 2 < NQSTEPS) ? (kt + 2) : (NQSTEPS - 1);
            DMA_A(A0, ks0 + kn);
            __builtin_amdgcn_sched_barrier(0);
            const int kw = ((kt + 3 < NQSTEPS) ? (kt + 3) : (NQSTEPS - 1)) * BK;
            ISSUEW(1, kw);
            COMPUTE(A1, B1);
            STAGEW(0, B0);
            SYNCC;
        }
    }

    // epilogue: kq==0 writes bias+acc to out; kq>0 writes acc to partials.
    float* const dst = (kq == 0) ? out : (wsP + (size_t)(kq - 1) * OUT_ELEMS);
    #pragma unroll
    for (int nf = 0; nf < 2; ++nf) {
        const int col = n0 + wn * 32 + nf * 16 + (lane & 15);
        const float bv = (kq == 0) ? bias[col] : 0.f;
        #pragma unroll
        for (int mf = 0; mf < 4; ++mf) {
            const f32x4 a =
                (nf == 0) ? (mf == 0 ? acc00 : mf == 1 ? acc10 : mf == 2 ? acc20 : acc30)
                          : (mf == 0 ? acc01 : mf == 1 ? acc11 : mf == 2 ? acc21 : acc31);
            #pragma unroll
            for (int j = 0; j < 4; ++j) {
                int r = wm * 64 + mf * 16 + (lane >> 4) * 4 + j;
                float v = a[j] + bv;
                float* o = (r < 128) ? (dst + (size_t)r * N_TOT + col)
                                     : (dst + HALF_M + (size_t)(r - 128) * N_TOT + col);
                *o = v;
            }
        }
    }
}

extern "C" void kernel_launch(void* const* d_in, const int* in_sizes, int n_in,
                              void* d_out, int out_size, void* d_ws, size_t ws_size,
                              hipStream_t stream) {
    const float* x0 = (const float*)d_in[0];
    const float* x1 = (const float*)d_in[1];
    const float* W  = (const float*)d_in[2];
    const float* b  = (const float*)d_in[3];
    float* out = (float*)d_out;

    const size_t wsT_bytes = (size_t)KSTEPS_TOT * TILE_BYTES;   // 8.4 MB

    unsigned short* wsT = (unsigned short*)d_ws;
    float* wsP = (float*)((char*)d_ws + wsT_bytes);

    cvtT_kernel<<<2048, 256, 0, stream>>>(x0, x1, wsT);
    gemm_ws<<<512, 1024, 0, stream>>>(W, b, wsT, out, wsP);
    combine_kernel<<<2048, 256, 0, stream>>>(out, wsP, wsP + OUT_ELEMS,
                                             wsP + 2 * OUT_ELEMS);
}

// Round 7
// 317.904 us; speedup vs baseline: 1.1975x; 1.1975x over previous
//
#include <hip/hip_runtime.h>
#include <hip/hip_bf16.h>

typedef __bf16 bf16x8 __attribute__((ext_vector_type(8)));
typedef float  f32x4  __attribute__((ext_vector_type(4)));

#define N_TOT   16384
#define K_TOT   16384
#define HALF_M  ((size_t)128 * 16384)
#define BN      128
#define BK      64
#define KSPLIT  4
#define KQ_LEN  (K_TOT / KSPLIT)      // 4096
#define NQSTEPS (KQ_LEN / BK)         // 64
#define OUT_ELEMS ((size_t)256 * 16384)

__device__ __forceinline__ unsigned short f2bf(float f) {
    __hip_bfloat16 h = __float2bfloat16(f);
    return __builtin_bit_cast(unsigned short, h);
}

// Swizzled byte offset: 128-B rows, 16-B granules, XOR row&7 into granule idx.
__device__ __forceinline__ int swz(int row, int g) {
    return row * 128 + (((g ^ (row & 7)) & 7) << 4);
}

// One-time T = concat(x0,x1) fp32 -> bf16 into workspace (linear row-major).
__global__ void cvtT_kernel(const float* __restrict__ x0,
                            const float* __restrict__ x1,
                            unsigned short* __restrict__ wsT) {
    size_t i = (size_t)blockIdx.x * blockDim.x + threadIdx.x;  // 0..524287
    size_t e = i * 8;
    const float* src = (e < HALF_M) ? (x0 + e) : (x1 + (e - HALF_M));
    float4 a = ((const float4*)src)[0];
    float4 b = ((const float4*)src)[1];
    union { unsigned short u[8]; uint4 v; } o;
    o.u[0] = f2bf(a.x); o.u[1] = f2bf(a.y); o.u[2] = f2bf(a.z); o.u[3] = f2bf(a.w);
    o.u[4] = f2bf(b.x); o.u[5] = f2bf(b.y); o.u[6] = f2bf(b.z); o.u[7] = f2bf(b.w);
    ((uint4*)wsT)[i] = o.v;
}

// out += p0 + p1 + p2 (fixed order -> deterministic)
__global__ void combine_kernel(float* __restrict__ out,
                               const float* __restrict__ p0,
                               const float* __restrict__ p1,
                               const float* __restrict__ p2) {
    const size_t n4 = OUT_ELEMS / 4;   // 1048576 float4
    size_t i = (size_t)blockIdx.x * blockDim.x + threadIdx.x;
    for (; i < n4; i += (size_t)gridDim.x * blockDim.x) {
        float4 o = ((const float4*)out)[i];
        float4 a = ((const float4*)p0)[i];
        float4 b = ((const float4*)p1)[i];
        float4 c = ((const float4*)p2)[i];
        o.x += a.x + b.x + c.x;  o.y += a.y + b.y + c.y;
        o.z += a.z + b.z + c.z;  o.w += a.w + b.w + c.w;
        ((float4*)out)[i] = o;
    }
}

// ---- prefetch/stage macros (depth-2, static register sets) ----
#define ISSUEW(S, k0) do {                                                    \
    const uint4* _p = (const uint4*)(arow_w + (k0));                          \
    w##S##_0 = _p[0]; w##S##_1 = _p[1];                                       \
    const float4* _q = (const float4*)(brow + (k0));                          \
    wb##S##_0 = _q[0]; wb##S##_1 = _q[1];                                     \
} while (0)

#define STAGEW(S, Ab, Bb) do {                                                \
    *(uint4*)((Ab) + aw0) = w##S##_0;                                         \
    *(uint4*)((Ab) + aw1) = w##S##_1;                                         \
    union { unsigned short u[8]; uint4 v; } _tb;                              \
    _tb.u[0]=f2bf(wb##S##_0.x); _tb.u[1]=f2bf(wb##S##_0.y);                   \
    _tb.u[2]=f2bf(wb##S##_0.z); _tb.u[3]=f2bf(wb##S##_0.w);                   \
    _tb.u[4]=f2bf(wb##S##_1.x); _tb.u[5]=f2bf(wb##S##_1.y);                   \
    _tb.u[6]=f2bf(wb##S##_1.z); _tb.u[7]=f2bf(wb##S##_1.w);                   \
    *(uint4*)((Bb) + bw) = _tb.v;                                             \
} while (0)

// 16 waves as 4M x 4N over 256M x 128N: wave owns 64M x 32N.
// 8 A-reads + 4 B-reads + 16 MFMA per step.
#define COMPUTE(Ab, Bb) do {                                                  \
    bf16x8 _b00 = *(const bf16x8*)((Bb) + boff00);                            \
    bf16x8 _b01 = *(const bf16x8*)((Bb) + boff01);                            \
    bf16x8 _b10 = *(const bf16x8*)((Bb) + boff10);                            \
    bf16x8 _b11 = *(const bf16x8*)((Bb) + boff11);                            \
    bf16x8 _a;                                                                \
    _a = *(const bf16x8*)((Ab) + aoff00);                                     \
    acc00 = __builtin_amdgcn_mfma_f32_16x16x32_bf16(_a, _b00, acc00, 0, 0, 0);\
    acc01 = __builtin_amdgcn_mfma_f32_16x16x32_bf16(_a, _b10, acc01, 0, 0, 0);\
    _a = *(const bf16x8*)((Ab) + aoff01);                                     \
    acc00 = __builtin_amdgcn_mfma_f32_16x16x32_bf16(_a, _b01, acc00, 0, 0, 0);\
    acc01 = __builtin_amdgcn_mfma_f32_16x16x32_bf16(_a, _b11, acc01, 0, 0, 0);\
    _a = *(const bf16x8*)((Ab) + aoff10);                                     \
    acc10 = __builtin_amdgcn_mfma_f32_16x16x32_bf16(_a, _b00, acc10, 0, 0, 0);\
    acc11 = __builtin_amdgcn_mfma_f32_16x16x32_bf16(_a, _b10, acc11, 0, 0, 0);\
    _a = *(const bf16x8*)((Ab) + aoff11);                                     \
    acc10 = __builtin_amdgcn_mfma_f32_16x16x32_bf16(_a, _b01, acc10, 0, 0, 0);\
    acc11 = __builtin_amdgcn_mfma_f32_16x16x32_bf16(_a, _b11, acc11, 0, 0, 0);\
    _a = *(const bf16x8*)((Ab) + aoff20);                                     \
    acc20 = __builtin_amdgcn_mfma_f32_16x16x32_bf16(_a, _b00, acc20, 0, 0, 0);\
    acc21 = __builtin_amdgcn_mfma_f32_16x16x32_bf16(_a, _b10, acc21, 0, 0, 0);\
    _a = *(const bf16x8*)((Ab) + aoff21);                                     \
    acc20 = __builtin_amdgcn_mfma_f32_16x16x32_bf16(_a, _b01, acc20, 0, 0, 0);\
    acc21 = __builtin_amdgcn_mfma_f32_16x16x32_bf16(_a, _b11, acc21, 0, 0, 0);\
    _a = *(const bf16x8*)((Ab) + aoff30);                                     \
    acc30 = __builtin_amdgcn_mfma_f32_16x16x32_bf16(_a, _b00, acc30, 0, 0, 0);\
    acc31 = __builtin_amdgcn_mfma_f32_16x16x32_bf16(_a, _b10, acc31, 0, 0, 0);\
    _a = *(const bf16x8*)((Ab) + aoff31);                                     \
    acc30 = __builtin_amdgcn_mfma_f32_16x16x32_bf16(_a, _b01, acc30, 0, 0, 0);\
    acc31 = __builtin_amdgcn_mfma_f32_16x16x32_bf16(_a, _b11, acc31, 0, 0, 0);\
} while (0)

#define SYNC do {                                                             \
    asm volatile("s_waitcnt lgkmcnt(0)" ::: "memory");                        \
    __builtin_amdgcn_s_barrier();                                             \
    __builtin_amdgcn_sched_barrier(0);                                        \
} while (0)

// GEMM: grid 512 = 128 n-strips x 4 k-quarters. XCD-ALIGNED mapping:
// XCD assignment is bid%8 (m09 round-robin), so kq=(bid&7)>>1 puts exactly
// ONE 2.1 MB wsT k-slice on each XCD's 4 MB L2 (round 5 had two slices ->
// 4.2 MB -> thrash to L3). nstrip=(bid>>3)*2+(bid&1) keeps the map bijective.
__global__ __launch_bounds__(1024, 4)
void gemm_ws(const float* __restrict__ W, const float* __restrict__ bias,
             const unsigned short* __restrict__ wsT,
             float* __restrict__ out, float* __restrict__ wsP)
{
    __shared__ uint4 smem_[(2 * 32768 + 2 * 16384) / 16];   // 96 KiB
    char* const sm = (char*)smem_;
    char* const A0 = sm;                       // A: 256 rows x 128 B
    char* const A1 = sm + 32768;
    char* const B0 = sm + 65536;               // B: 128 rows x 128 B
    char* const B1 = sm + 65536 + 16384;

    const int tid  = threadIdx.x;
    const int lane = tid & 63;
    const int wave = tid >> 6;
    const int wm = wave >> 2;                  // 0..3 (64 M rows)
    const int wn = wave & 3;                   // 0..3 (32 N cols)
    const int bid    = blockIdx.x;
    const int kq     = (bid & 7) >> 1;         // one k-quarter per XCD
    const int nstrip = ((bid >> 3) << 1) + (bid & 1);
    const int n0     = nstrip * BN;
    const int kbase  = kq * KQ_LEN;

    // staging geometry
    const int ra  = tid >> 2;                  // A row 0..255
    const int pa  = tid & 3;                   // 32-B chunk of 128-B row
    const int rbs = tid >> 3;                  // B row 0..127

    const unsigned short* arow_w = wsT + (size_t)ra * K_TOT + kbase + pa * 16;
    const float* brow = W + (size_t)(n0 + rbs) * K_TOT + kbase + (tid & 7) * 8;

    const int aw0 = swz(ra, 2 * pa);
    const int aw1 = swz(ra, 2 * pa + 1);
    const int bw  = swz(rbs, tid & 7);

    // compute-side LDS read offsets
    const int aoff00 = swz(wm * 64 +  0 + (lane & 15), 0 + (lane >> 4));
    const int aoff01 = swz(wm * 64 +  0 + (lane & 15), 4 + (lane >> 4));
    const int aoff10 = swz(wm * 64 + 16 + (lane & 15), 0 + (lane >> 4));
    const int aoff11 = swz(wm * 64 + 16 + (lane & 15), 4 + (lane >> 4));
    const int aoff20 = swz(wm * 64 + 32 + (lane & 15), 0 + (lane >> 4));
    const int aoff21 = swz(wm * 64 + 32 + (lane & 15), 4 + (lane >> 4));
    const int aoff30 = swz(wm * 64 + 48 + (lane & 15), 0 + (lane >> 4));
    const int aoff31 = swz(wm * 64 + 48 + (lane & 15), 4 + (lane >> 4));
    const int boff00 = swz(wn * 32 +  0 + (lane & 15), 0 + (lane >> 4));
    const int boff01 = swz(wn * 32 +  0 + (lane & 15), 4 + (lane >> 4));
    const int boff10 = swz(wn * 32 + 16 + (lane & 15), 0 + (lane >> 4));
    const int boff11 = swz(wn * 32 + 16 + (lane & 15), 4 + (lane >> 4));

    f32x4 acc00 = {0.f,0.f,0.f,0.f}, acc01 = {0.f,0.f,0.f,0.f};
    f32x4 acc10 = {0.f,0.f,0.f,0.f}, acc11 = {0.f,0.f,0.f,0.f};
    f32x4 acc20 = {0.f,0.f,0.f,0.f}, acc21 = {0.f,0.f,0.f,0.f};
    f32x4 acc30 = {0.f,0.f,0.f,0.f}, acc31 = {0.f,0.f,0.f,0.f};

    uint4  w0_0, w0_1, w1_0, w1_1;
    float4 wb0_0, wb0_1, wb1_0, wb1_1;

    ISSUEW(0, 0);
    ISSUEW(1, BK);
    STAGEW(0, A0, B0);
    SYNC;

    for (int kt = 0; kt < NQSTEPS; kt += 2) {
        if (kt + 2 < NQSTEPS) ISSUEW(0, (kt + 2) * BK);
        COMPUTE(A0, B0);
        STAGEW(1, A1, B1);
        SYNC;
        if (kt + 3 < NQSTEPS) ISSUEW(1, (kt + 3) * BK);
        COMPUTE(A1, B1);
        if (kt + 2 < NQSTEPS) STAGEW(0, A0, B0);
        SYNC;
    }

    // epilogue: kq==0 writes bias+acc to out; kq>0 writes acc to partial buf.
    float* const dst = (kq == 0) ? out : (wsP + (size_t)(kq - 1) * OUT_ELEMS);
    #pragma unroll
    for (int nf = 0; nf < 2; ++nf) {
        const int col = n0 + wn * 32 + nf * 16 + (lane & 15);
        const float bv = (kq == 0) ? bias[col] : 0.f;
        #pragma unroll
        for (int mf = 0; mf < 4; ++mf) {
            const f32x4 a =
                (nf == 0) ? (mf == 0 ? acc00 : mf == 1 ? acc10 : mf == 2 ? acc20 : acc30)
                          : (mf == 0 ? acc01 : mf == 1 ? acc11 : mf == 2 ? acc21 : acc31);
            #pragma unroll
            for (int j = 0; j < 4; ++j) {
                int r = wm * 64 + mf * 16 + (lane >> 4) * 4 + j;
                float v = a[j] + bv;
                float* o = (r < 128) ? (dst + (size_t)r * N_TOT + col)
                                     : (dst + HALF_M + (size_t)(r - 128) * N_TOT + col);
                *o = v;
            }
        }
    }
}

extern "C" void kernel_launch(void* const* d_in, const int* in_sizes, int n_in,
                              void* d_out, int out_size, void* d_ws, size_t ws_size,
                              hipStream_t stream) {
    const float* x0 = (const float*)d_in[0];
    const float* x1 = (const float*)d_in[1];
    const float* W  = (const float*)d_in[2];
    const float* b  = (const float*)d_in[3];
    float* out = (float*)d_out;

    const size_t wsT_bytes = (size_t)256 * 16384 * sizeof(unsigned short);  // 8.4 MB

    unsigned short* wsT = (unsigned short*)d_ws;
    float* wsP = (float*)((char*)d_ws + wsT_bytes);

    cvtT_kernel<<<2048, 256, 0, stream>>>(x0, x1, wsT);
    gemm_ws<<<512, 1024, 0, stream>>>(W, b, wsT, out, wsP);
    combine_kernel<<<2048, 256, 0, stream>>>(out, wsP, wsP + OUT_ELEMS,
                                             wsP + 2 * OUT_ELEMS);
}